// Round 21
// baseline (120.776 us; speedup 1.0000x reference)
//
#include <hip/hip_runtime.h>
#include <stdint.h>

typedef unsigned short u16;
typedef long long i64;
typedef __attribute__((ext_vector_type(4))) float f32x4;
typedef __attribute__((ext_vector_type(8))) short bf16x8;
typedef __attribute__((ext_vector_type(4))) int i32x4;
typedef __attribute__((ext_vector_type(2))) unsigned int u32x2;

#define SEQ 4096
#define DIM 256
// base scale = 1/sqrt(256)*log2(e); Q folds x4, K folds 0.25 (fp8 range balance)
#define QS4 0.36067376f

__device__ __forceinline__ u16 f2bf(float f) {
  union { float f; uint32_t u; } v; v.f = f;
  uint32_t r = (v.u + 0x7FFFu + ((v.u >> 16) & 1u)) >> 16;
  return (u16)r;
}

__device__ __forceinline__ float bf2f(u16 u) {
  union { uint32_t u; float f; } v; v.u = ((uint32_t)u) << 16;
  return v.f;
}

__device__ __forceinline__ uint8_t f2fp8(float f) {
  return (uint8_t)__builtin_amdgcn_cvt_pk_fp8_f32(f, 0.f, 0, false);
}

__device__ __forceinline__ void gload_lds16(const void* g, void* lds) {
  __builtin_amdgcn_global_load_lds(
      (const __attribute__((address_space(1))) uint32_t*)g,
      (__attribute__((address_space(3))) uint32_t*)lds, 16, 0, 0);
}

__device__ __forceinline__ f32x4 mfma8(i64 a, i64 b, f32x4 c) {
  return __builtin_amdgcn_mfma_f32_16x16x32_fp8_fp8(a, b, c, 0, 0, 0);
}

// ---------------- weight transpose + bf16 cast (scales folded) ---------------
__global__ __launch_bounds__(256) void wt_kernel(const float* __restrict__ Wq,
                                                 const float* __restrict__ Wk,
                                                 const float* __restrict__ Wv,
                                                 u16* __restrict__ wt) {
  int b = blockIdx.x;              // 0..767
  int w = b >> 8;                  // which matrix
  int n = b & 255;                 // output column -> wt row
  const float* W = (w == 0) ? Wq : ((w == 1) ? Wk : Wv);
  float scale = (w == 0) ? QS4 : ((w == 1) ? 0.25f : 1.0f);
  int k = threadIdx.x;
  wt[(w * 256 + n) * 256 + k] = f2bf(W[k * 256 + n] * scale);
}

// ---------------- QKV v2 (verified round 20): dbuf staging, f32x4 x-loads ----
__global__ __launch_bounds__(256) void qkv_kernel(
    const float* __restrict__ x, const float* __restrict__ bq,
    const float* __restrict__ bk, const float* __restrict__ bv,
    const u16* __restrict__ wt, uint8_t* __restrict__ qs,
    uint8_t* __restrict__ kk, char* __restrict__ vt) {
  __shared__ __align__(16) char lds_b[65536];   // 2 x 32KB weight chunks
  __shared__ __align__(16) u16 lds_v[4096];     // 8KB V-transpose buffer
  int tid = threadIdx.x;
  int w = tid >> 6, l = tid & 63;
  int a = l & 15, g = l >> 4;
  int rowbase = blockIdx.x * 64;

  uint32_t wso[8];
#pragma unroll
  for (int j = 0; j < 8; ++j) {
    uint32_t inst = w * 8 + j;
    uint32_t flat = inst * 1024 + l * 16;
    uint32_t row = flat >> 9;
    uint32_t c5 = (flat >> 4) & 31;
    uint32_t sc = (c5 & ~7u) | ((c5 ^ row) & 7u);
    wso[j] = row * 512 + sc * 16;
  }
  uint32_t bro[8];
#pragma unroll
  for (int ks = 0; ks < 8; ++ks) {
    uint32_t c5 = ks * 4 + g;
    uint32_t sc = (c5 & ~7u) | ((c5 ^ (a & 7u)) & 7u);
    bro[ks] = (uint32_t)a * 512 + sc * 16;
  }

  bf16x8 afr[8];
  {
    int row = rowbase + w * 16 + a;
    const f32x4* xr4 = (const f32x4*)(x + (size_t)row * 256);
#pragma unroll
    for (int ks = 0; ks < 8; ++ks) {
      int q4 = ks * 8 + g * 2;
      f32x4 lo = xr4[q4], hi = xr4[q4 + 1];
      union { bf16x8 s; u16 u[8]; } fr;
      fr.u[0] = f2bf(lo[0]); fr.u[1] = f2bf(lo[1]);
      fr.u[2] = f2bf(lo[2]); fr.u[3] = f2bf(lo[3]);
      fr.u[4] = f2bf(hi[0]); fr.u[5] = f2bf(hi[1]);
      fr.u[6] = f2bf(hi[2]); fr.u[7] = f2bf(hi[3]);
      afr[ks] = fr.s;
    }
  }

#pragma unroll
  for (int j = 0; j < 8; ++j)
    gload_lds16((const char*)wt + wso[j], lds_b + (w * 8 + j) * 1024);

  int cur = 0;
  for (int it = 0; it < 12; ++it) {
    asm volatile("s_waitcnt vmcnt(0) lgkmcnt(0)" ::: "memory");
    __builtin_amdgcn_s_barrier();
    __builtin_amdgcn_sched_barrier(0);
    if (it < 11) {
#pragma unroll
      for (int j = 0; j < 8; ++j)
        gload_lds16((const char*)wt + (size_t)(it + 1) * 32768 + wso[j],
                    lds_b + (cur ^ 1) * 32768 + (w * 8 + j) * 1024);
    }
    int w3 = it >> 2, qn = it & 3;
    f32x4 acc[4];
#pragma unroll
    for (int n0 = 0; n0 < 4; ++n0) acc[n0] = (f32x4){0.f, 0.f, 0.f, 0.f};
#pragma unroll
    for (int ks = 0; ks < 8; ++ks) {
#pragma unroll
      for (int n0 = 0; n0 < 4; ++n0) {
        bf16x8 bfr = *(const bf16x8*)(lds_b + cur * 32768 + bro[ks] + n0 * 8192);
        acc[n0] = __builtin_amdgcn_mfma_f32_16x16x32_bf16(afr[ks], bfr, acc[n0], 0, 0, 0);
      }
    }
    const float* bias = (w3 == 0) ? bq : ((w3 == 1) ? bk : bv);
    if (w3 < 2) {
      uint8_t* out8 = (w3 == 0) ? qs : kk;
      float bscale = (w3 == 0) ? QS4 : 0.25f;
#pragma unroll
      for (int n0 = 0; n0 < 4; ++n0) {
        int col = qn * 64 + n0 * 16 + a;
        float bb = bias[col] * bscale;
#pragma unroll
        for (int r = 0; r < 4; ++r) {
          int row = rowbase + w * 16 + g * 4 + r;
          out8[(size_t)row * 256 + col] = f2fp8(acc[n0][r] + bb);
        }
      }
    } else {
#pragma unroll
      for (int n0 = 0; n0 < 4; ++n0) {
        int col = qn * 64 + n0 * 16 + a;
        float bb = bias[col];
        int dl = n0 * 16 + a;
#pragma unroll
        for (int r = 0; r < 4; ++r) {
          int m = w * 16 + g * 4 + r;
          uint32_t byteoff =
              (uint32_t)dl * 128 + ((((uint32_t)m >> 3) ^ ((uint32_t)dl & 7)) << 4) + (m & 7) * 2;
          *(u16*)((char*)lds_v + byteoff) = f2bf(acc[n0][r] + bb);
        }
      }
      asm volatile("s_waitcnt lgkmcnt(0)" ::: "memory");
      __builtin_amdgcn_s_barrier();   // lds_v writes visible; no vmcnt drain
      {
        int dl = tid >> 2;
        size_t base = (size_t)blockIdx.x * 32768 + (size_t)(qn * 64 + dl) * 128;
#pragma unroll
        for (int cc = 0; cc < 2; ++cc) {
          uint32_t c = (tid & 3) + cc * 4;
          i32x4 vd = *(const i32x4*)((const char*)lds_v + dl * 128 + ((c ^ (dl & 7)) << 4));
          *(i32x4*)(vt + base + c * 16) = vd;
        }
      }
    }
    cur ^= 1;
  }
}

// ---------------- flash attention v21: v19 + wave-parity phase stagger -------
// v19 verified structure (QBLK=128, split=2, ONE barrier/tile, P dbuf, fp8
// Q/K + bf16 V/P, absmax 1.95e-3). New: even waves run QK(t)->Pwrite->PV(t-1),
// odd waves run PV(t-1)->QK(t)->Pwrite (both legal: all operands are
// barrier-ready, P slots disjoint). De-synchronizes the per-SIMD LDS-read and
// MFMA bursts -> s_setprio gets role diversity to arbitrate (T5 regime).
// h=1 partial O stored bf16 (halves combine traffic; <=3e-4 error).
#define VVB 32768u
#define PVB 98304u

#define PV_STEP(SLOT)                                                          \
  {                                                                            \
    bf16x8 pfr[2][2];                                                          \
    _Pragma("unroll") for (int mt = 0; mt < 2; ++mt)                           \
    _Pragma("unroll") for (int j2 = 0; j2 < 2; ++j2)                           \
        pfr[mt][j2] = *(const bf16x8*)(lds + PVB + (SLOT) * 16384 + pro[j2] +  \
                                       mt * 2048);                             \
    __builtin_amdgcn_s_setprio(1);                                             \
    _Pragma("unroll") for (int mt = 0; mt < 2; ++mt)                           \
    _Pragma("unroll") for (int j2 = 0; j2 < 2; ++j2)                           \
        lacc[mt] = __builtin_amdgcn_mfma_f32_16x16x32_bf16(pfr[mt][j2], ones,  \
                                                           lacc[mt], 0, 0, 0); \
    _Pragma("unroll") for (int d0 = 0; d0 < 8; ++d0)                           \
    _Pragma("unroll") for (int j2 = 0; j2 < 2; ++j2) {                         \
      bf16x8 vfr = *(const bf16x8*)(lds + VVB + (SLOT) * 32768 + vro[j2] +     \
                                    d0 * 2048);                                \
      o[0][d0] = __builtin_amdgcn_mfma_f32_16x16x32_bf16(pfr[0][j2], vfr, o[0][d0], 0, 0, 0); \
      o[1][d0] = __builtin_amdgcn_mfma_f32_16x16x32_bf16(pfr[1][j2], vfr, o[1][d0], 0, 0, 0); \
    }                                                                          \
    __builtin_amdgcn_s_setprio(0);                                             \
  }

#define QKEXP(CUR)                                                             \
  {                                                                            \
    f32x4 sc[2][2];                                                            \
    _Pragma("unroll") for (int mt = 0; mt < 2; ++mt)                           \
    _Pragma("unroll") for (int n = 0; n < 2; ++n)                              \
        sc[mt][n] = (f32x4){0.f, 0.f, 0.f, 0.f};                               \
    __builtin_amdgcn_s_setprio(1);                                             \
    _Pragma("unroll") for (int n = 0; n < 2; ++n)                              \
    _Pragma("unroll") for (int j = 0; j < 8; ++j) {                            \
      i64 kfr = *(const i64*)(lds + (CUR) * 16384 + kro[j] + n * 4096);        \
      sc[0][n] = mfma8(kfr, qfr[0][j], sc[0][n]);                              \
      sc[1][n] = mfma8(kfr, qfr[1][j], sc[1][n]);                              \
    }                                                                          \
    __builtin_amdgcn_s_setprio(0);                                             \
    _Pragma("unroll") for (int mt = 0; mt < 2; ++mt)                           \
    _Pragma("unroll") for (int n = 0; n < 2; ++n) {                            \
      float e0 = exp2f(sc[mt][n][0]);                                          \
      float e1 = exp2f(sc[mt][n][1]);                                          \
      float e2 = exp2f(sc[mt][n][2]);                                          \
      float e3 = exp2f(sc[mt][n][3]);                                          \
      uint32_t p0 = (uint32_t)f2bf(e0) | ((uint32_t)f2bf(e1) << 16);           \
      uint32_t p1 = (uint32_t)f2bf(e2) | ((uint32_t)f2bf(e3) << 16);           \
      u32x2 pk = {p0, p1};                                                     \
      *(u32x2*)(lds + PVB + (CUR) * 16384 + pwo[n] + mt * 2048) = pk;          \
    }                                                                          \
  }

#define TILE(CUR, DO_PV, DO_K)                                                 \
  {                                                                            \
    asm volatile("s_waitcnt vmcnt(0) lgkmcnt(0)" ::: "memory");                \
    __builtin_amdgcn_s_barrier();                                              \
    __builtin_amdgcn_sched_barrier(0);                                         \
    _Pragma("unroll") for (int j = 0; j < 4; ++j)                              \
        gload_lds16(vstp + vso[j], lds + VVB + (CUR) * 32768 + (w * 4 + j) * 1024); \
    if (DO_K) {                                                                \
      gload_lds16(kstp + kso[0], lds + ((CUR) ^ 1) * 16384 + (w * 2 + 0) * 1024); \
      gload_lds16(kstp + kso[1], lds + ((CUR) ^ 1) * 16384 + (w * 2 + 1) * 1024); \
    }                                                                          \
    kstp += 16384;                                                             \
    vstp += 32768;                                                             \
    if (w & 1) {                                                               \
      if (DO_PV) PV_STEP((CUR) ^ 1)                                            \
      QKEXP(CUR)                                                               \
    } else {                                                                   \
      QKEXP(CUR)                                                               \
      if (DO_PV) PV_STEP((CUR) ^ 1)                                            \
    }                                                                          \
  }

__global__ __launch_bounds__(512, 1) void attn_kernel(
    const uint8_t* __restrict__ qs, const uint8_t* __restrict__ kk,
    const char* __restrict__ vt, float* __restrict__ out,
    u16* __restrict__ pOB, float* __restrict__ pl, int split) {
  __shared__ __align__(16) char lds[131072];
  int tid = threadIdx.x;
  int w = tid >> 6, l = tid & 63;
  int a = l & 15, g = l >> 4;
  int qq = w >> 1, sub = w & 1;
  int bx = blockIdx.x;
  int h, batch, qt;
  // XCD-pinning: (batch,h) <-> XCD pair; fp8 K + bf16 V halves stay L2-resident
  if (split == 2) { h = bx & 1; batch = (bx >> 1) & 3; qt = bx >> 3; }
  else            { h = 0;      batch = (bx >> 1) & 3; qt = ((bx >> 3) << 1) | (bx & 1); }
  int ntHalf = (split == 2) ? 16 : 32;

  uint32_t a7 = a & 7;
  uint32_t kro[8], vro[2], pro[2], pwo[2], kso[2], vso[4];
  {
    uint32_t row = (uint32_t)(sub * 32 + a);   // K fp8: 64 rows x 256B (v18 form)
#pragma unroll
    for (int j = 0; j < 8; ++j) {
      uint32_t c4 = j * 2 + (g >> 1);
      kro[j] = row * 256 + (((c4 & ~7u) | ((c4 ^ a7) & 7u)) << 4) + (g & 1) * 8;
    }
  }
#pragma unroll
  for (int j2 = 0; j2 < 2; ++j2)               // V bf16: 256 rows x 128B (v12)
    vro[j2] = (uint32_t)(sub * 128 + a) * 128 +
              ((((uint32_t)(j2 * 4 + g)) ^ a7) << 4);
  {
    uint32_t q = (uint32_t)(qq * 32 + a);      // P bf16: 128 rows x 128B (v12)
#pragma unroll
    for (int j2 = 0; j2 < 2; ++j2)
      pro[j2] = q * 128 + ((((uint32_t)(j2 * 4 + g)) ^ a7) << 4);
#pragma unroll
    for (int n = 0; n < 2; ++n)
      pwo[n] = q * 128 +
               ((((uint32_t)(sub * 4 + n * 2 + (g >> 1))) ^ a7) << 4) + (g & 1) * 8;
  }
#pragma unroll
  for (int j = 0; j < 2; ++j) {                // K stage (v18 form, 16KB tile)
    uint32_t inst = w * 2 + j, flat = inst * 1024 + l * 16;
    uint32_t row = flat >> 8, c4 = (flat >> 4) & 15;
    kso[j] = row * 256 + (((c4 & ~7u) | ((c4 ^ (row & 7u)) & 7u)) << 4);
  }
#pragma unroll
  for (int j = 0; j < 4; ++j) {                // V stage (v12 form, 32KB tile)
    uint32_t inst = w * 4 + j, flat = inst * 1024 + l * 16;
    uint32_t row = flat >> 7, c3 = (flat >> 4) & 7;
    vso[j] = row * 128 + ((c3 ^ (row & 7)) << 4);
  }

  // Q fragments fp8 (B-operand): 32 q-rows of quarter qq (verified layout)
  i64 qfr[2][8];
  {
    const uint8_t* qp = qs + (size_t)(batch * SEQ + qt * 128) * 256;
#pragma unroll
    for (int mt = 0; mt < 2; ++mt)
#pragma unroll
      for (int j = 0; j < 8; ++j)
        qfr[mt][j] = *(const i64*)(qp + (size_t)(qq * 32 + mt * 16 + a) * 256 +
                                   j * 32 + g * 8);
  }

  f32x4 o[2][8];   // O[32q][128d] (d-half sub), unnormalized partial
  f32x4 lacc[2];   // partial row-sums of P
#pragma unroll
  for (int mt = 0; mt < 2; ++mt) {
    lacc[mt] = (f32x4){0.f, 0.f, 0.f, 0.f};
#pragma unroll
    for (int d0 = 0; d0 < 8; ++d0) o[mt][d0] = (f32x4){0.f, 0.f, 0.f, 0.f};
  }
  const short ob = (short)0x3F80;
  bf16x8 ones = {ob, ob, ob, ob, ob, ob, ob, ob};

  const uint8_t* kstp = kk + (size_t)batch * SEQ * 256 + (size_t)h * 2048 * 256;
  const char* vstp = vt + (size_t)batch * 64 * 32768 + (size_t)h * 32 * 32768;

  // prologue: stage K(0) into slot 0
  gload_lds16(kstp + kso[0], lds + (w * 2 + 0) * 1024);
  gload_lds16(kstp + kso[1], lds + (w * 2 + 1) * 1024);
  kstp += 16384;

  TILE(0, false, true)                       // t = 0
  for (int tp = 0; tp < ntHalf - 1; ++tp) {  // t = 1..nt-2
    TILE(1, true, true)
    TILE(0, true, true)
  }
  TILE(1, true, false)                       // t = nt-1 (no K stage)

  // ---- epilogue: PV(nt-1) from slot 1, then store partials ----------------
  asm volatile("s_waitcnt vmcnt(0) lgkmcnt(0)" ::: "memory");
  __builtin_amdgcn_s_barrier();
  __builtin_amdgcn_sched_barrier(0);
  PV_STEP(1)

  size_t obase = (size_t)(batch * SEQ + qt * 128 + qq * 32) * 256 + sub * 128;
  if (h == 0) {
#pragma unroll
    for (int mt = 0; mt < 2; ++mt)
#pragma unroll
      for (int r = 0; r < 4; ++r) {
#pragma unroll
        for (int d0 = 0; d0 < 8; ++d0)
          out[obase + (size_t)(mt * 16 + g * 4 + r) * 256 + d0 * 16 + a] = o[mt][d0][r];
      }
  } else {
#pragma unroll
    for (int mt = 0; mt < 2; ++mt)
#pragma unroll
      for (int r = 0; r < 4; ++r) {
#pragma unroll
        for (int d0 = 0; d0 < 8; ++d0)
          pOB[obase + (size_t)(mt * 16 + g * 4 + r) * 256 + d0 * 16 + a] =
              f2bf(o[mt][d0][r]);
      }
  }
  if (a == 0 && sub == 0) {
#pragma unroll
    for (int mt = 0; mt < 2; ++mt)
#pragma unroll
      for (int r = 0; r < 4; ++r)
        pl[h * 16384 + (batch * 32 + qt) * 128 + qq * 32 + mt * 16 + g * 4 + r] =
            lacc[mt][r];
  }
}

// ---------------- combine: out = (OA + OB) / (lA + lB), OB bf16 --------------
__global__ __launch_bounds__(256) void combine_kernel(float* __restrict__ out,
                                                      const u16* __restrict__ pOB,
                                                      const float* __restrict__ pl,
                                                      int split) {
  int b = blockIdx.x;            // 16384 rows
  int tid = threadIdx.x;
  int batch = b >> 12;
  int rem = b & 4095;
  int qt = rem >> 7, ql = rem & 127;
  size_t idx = (size_t)b * 256 + tid;
  int li = (batch * 32 + qt) * 128 + ql;
  float lA = pl[li];
  float v;
  if (split == 2) {
    float lB = pl[16384 + li];
    v = (out[idx] + bf2f(pOB[idx])) / (lA + lB);
  } else {
    v = out[idx] / lA;
  }
  out[idx] = v;
}

extern "C" void kernel_launch(void* const* d_in, const int* in_sizes, int n_in,
                              void* d_out, int out_size, void* d_ws, size_t ws_size,
                              hipStream_t stream) {
  const float* x = (const float*)d_in[0];
  const float* Wq = (const float*)d_in[1];
  const float* bq = (const float*)d_in[2];
  const float* Wk = (const float*)d_in[3];
  const float* bk = (const float*)d_in[4];
  const float* Wv = (const float*)d_in[5];
  const float* bv = (const float*)d_in[6];
  char* ws = (char*)d_ws;
  u16* wt = (u16*)ws;                              // 384KB @0
  uint8_t* qs = (uint8_t*)(ws + 0x60000);          // 4MB fp8 Q
  uint8_t* kk = (uint8_t*)(ws + 0x460000);         // 4MB fp8 K
  char* vt = ws + 0x860000;                        // 8MB bf16 V^T
  float* pl = (float*)(ws + 0x1060000);            // 128KB
  u16* pOB = (u16*)(ws + 0x1080000);               // 8MB bf16 partial O (h=1)
  int split = (ws_size >= 0x1880000ull) ? 2 : 1;
  wt_kernel<<<dim3(768), dim3(256), 0, stream>>>(Wq, Wk, Wv, wt);
  qkv_kernel<<<dim3(256), dim3(256), 0, stream>>>(x, bq, bk, bv, wt, qs, kk, vt);
  attn_kernel<<<dim3(split * 128), dim3(512), 0, stream>>>(qs, kk, vt, (float*)d_out,
                                                           pOB, pl, split);
  combine_kernel<<<dim3(16384), dim3(256), 0, stream>>>((float*)d_out, pOB, pl, split);
}

// Round 22
// 114.100 us; speedup vs baseline: 1.0585x; 1.0585x over previous
//
#include <hip/hip_runtime.h>
#include <stdint.h>

typedef unsigned short u16;
typedef long long i64;
typedef __attribute__((ext_vector_type(4))) float f32x4;
typedef __attribute__((ext_vector_type(8))) short bf16x8;
typedef __attribute__((ext_vector_type(4))) int i32x4;
typedef __attribute__((ext_vector_type(2))) unsigned int u32x2;

#define SEQ 4096
#define DIM 256
// base scale = 1/sqrt(256)*log2(e); Q folds x4, K folds 0.25 (fp8 range balance)
#define QS4 0.36067376f

__device__ __forceinline__ u16 f2bf(float f) {
  union { float f; uint32_t u; } v; v.f = f;
  uint32_t r = (v.u + 0x7FFFu + ((v.u >> 16) & 1u)) >> 16;
  return (u16)r;
}

__device__ __forceinline__ float bf2f(u16 u) {
  union { uint32_t u; float f; } v; v.u = ((uint32_t)u) << 16;
  return v.f;
}

__device__ __forceinline__ uint8_t f2fp8(float f) {
  return (uint8_t)__builtin_amdgcn_cvt_pk_fp8_f32(f, 0.f, 0, false);
}

__device__ __forceinline__ void gload_lds16(const void* g, void* lds) {
  __builtin_amdgcn_global_load_lds(
      (const __attribute__((address_space(1))) uint32_t*)g,
      (__attribute__((address_space(3))) uint32_t*)lds, 16, 0, 0);
}

__device__ __forceinline__ f32x4 mfma8(i64 a, i64 b, f32x4 c) {
  return __builtin_amdgcn_mfma_f32_16x16x32_fp8_fp8(a, b, c, 0, 0, 0);
}

// ---------------- weight transpose + bf16 cast (scales folded) ---------------
__global__ __launch_bounds__(256) void wt_kernel(const float* __restrict__ Wq,
                                                 const float* __restrict__ Wk,
                                                 const float* __restrict__ Wv,
                                                 u16* __restrict__ wt) {
  int b = blockIdx.x;              // 0..767
  int w = b >> 8;                  // which matrix
  int n = b & 255;                 // output column -> wt row
  const float* W = (w == 0) ? Wq : ((w == 1) ? Wk : Wv);
  float scale = (w == 0) ? QS4 : ((w == 1) ? 0.25f : 1.0f);
  int k = threadIdx.x;
  wt[(w * 256 + n) * 256 + k] = f2bf(W[k * 256 + n] * scale);
}

// ---------------- QKV v2 (verified round 20): dbuf staging, f32x4 x-loads ----
__global__ __launch_bounds__(256) void qkv_kernel(
    const float* __restrict__ x, const float* __restrict__ bq,
    const float* __restrict__ bk, const float* __restrict__ bv,
    const u16* __restrict__ wt, uint8_t* __restrict__ qs,
    uint8_t* __restrict__ kk, char* __restrict__ vt) {
  __shared__ __align__(16) char lds_b[65536];   // 2 x 32KB weight chunks
  __shared__ __align__(16) u16 lds_v[4096];     // 8KB V-transpose buffer
  int tid = threadIdx.x;
  int w = tid >> 6, l = tid & 63;
  int a = l & 15, g = l >> 4;
  int rowbase = blockIdx.x * 64;

  uint32_t wso[8];
#pragma unroll
  for (int j = 0; j < 8; ++j) {
    uint32_t inst = w * 8 + j;
    uint32_t flat = inst * 1024 + l * 16;
    uint32_t row = flat >> 9;
    uint32_t c5 = (flat >> 4) & 31;
    uint32_t sc = (c5 & ~7u) | ((c5 ^ row) & 7u);
    wso[j] = row * 512 + sc * 16;
  }
  uint32_t bro[8];
#pragma unroll
  for (int ks = 0; ks < 8; ++ks) {
    uint32_t c5 = ks * 4 + g;
    uint32_t sc = (c5 & ~7u) | ((c5 ^ (a & 7u)) & 7u);
    bro[ks] = (uint32_t)a * 512 + sc * 16;
  }

  bf16x8 afr[8];
  {
    int row = rowbase + w * 16 + a;
    const f32x4* xr4 = (const f32x4*)(x + (size_t)row * 256);
#pragma unroll
    for (int ks = 0; ks < 8; ++ks) {
      int q4 = ks * 8 + g * 2;
      f32x4 lo = xr4[q4], hi = xr4[q4 + 1];
      union { bf16x8 s; u16 u[8]; } fr;
      fr.u[0] = f2bf(lo[0]); fr.u[1] = f2bf(lo[1]);
      fr.u[2] = f2bf(lo[2]); fr.u[3] = f2bf(lo[3]);
      fr.u[4] = f2bf(hi[0]); fr.u[5] = f2bf(hi[1]);
      fr.u[6] = f2bf(hi[2]); fr.u[7] = f2bf(hi[3]);
      afr[ks] = fr.s;
    }
  }

#pragma unroll
  for (int j = 0; j < 8; ++j)
    gload_lds16((const char*)wt + wso[j], lds_b + (w * 8 + j) * 1024);

  int cur = 0;
  for (int it = 0; it < 12; ++it) {
    asm volatile("s_waitcnt vmcnt(0) lgkmcnt(0)" ::: "memory");
    __builtin_amdgcn_s_barrier();
    __builtin_amdgcn_sched_barrier(0);
    if (it < 11) {
#pragma unroll
      for (int j = 0; j < 8; ++j)
        gload_lds16((const char*)wt + (size_t)(it + 1) * 32768 + wso[j],
                    lds_b + (cur ^ 1) * 32768 + (w * 8 + j) * 1024);
    }
    int w3 = it >> 2, qn = it & 3;
    f32x4 acc[4];
#pragma unroll
    for (int n0 = 0; n0 < 4; ++n0) acc[n0] = (f32x4){0.f, 0.f, 0.f, 0.f};
#pragma unroll
    for (int ks = 0; ks < 8; ++ks) {
#pragma unroll
      for (int n0 = 0; n0 < 4; ++n0) {
        bf16x8 bfr = *(const bf16x8*)(lds_b + cur * 32768 + bro[ks] + n0 * 8192);
        acc[n0] = __builtin_amdgcn_mfma_f32_16x16x32_bf16(afr[ks], bfr, acc[n0], 0, 0, 0);
      }
    }
    const float* bias = (w3 == 0) ? bq : ((w3 == 1) ? bk : bv);
    if (w3 < 2) {
      uint8_t* out8 = (w3 == 0) ? qs : kk;
      float bscale = (w3 == 0) ? QS4 : 0.25f;
#pragma unroll
      for (int n0 = 0; n0 < 4; ++n0) {
        int col = qn * 64 + n0 * 16 + a;
        float bb = bias[col] * bscale;
#pragma unroll
        for (int r = 0; r < 4; ++r) {
          int row = rowbase + w * 16 + g * 4 + r;
          out8[(size_t)row * 256 + col] = f2fp8(acc[n0][r] + bb);
        }
      }
    } else {
#pragma unroll
      for (int n0 = 0; n0 < 4; ++n0) {
        int col = qn * 64 + n0 * 16 + a;
        float bb = bias[col];
        int dl = n0 * 16 + a;
#pragma unroll
        for (int r = 0; r < 4; ++r) {
          int m = w * 16 + g * 4 + r;
          uint32_t byteoff =
              (uint32_t)dl * 128 + ((((uint32_t)m >> 3) ^ ((uint32_t)dl & 7)) << 4) + (m & 7) * 2;
          *(u16*)((char*)lds_v + byteoff) = f2bf(acc[n0][r] + bb);
        }
      }
      asm volatile("s_waitcnt lgkmcnt(0)" ::: "memory");
      __builtin_amdgcn_s_barrier();   // lds_v writes visible; no vmcnt drain
      {
        int dl = tid >> 2;
        size_t base = (size_t)blockIdx.x * 32768 + (size_t)(qn * 64 + dl) * 128;
#pragma unroll
        for (int cc = 0; cc < 2; ++cc) {
          uint32_t c = (tid & 3) + cc * 4;
          i32x4 vd = *(const i32x4*)((const char*)lds_v + dl * 128 + ((c ^ (dl & 7)) << 4));
          *(i32x4*)(vt + base + c * 16) = vd;
        }
      }
    }
    cur ^= 1;
  }
}

// ---------------- flash attention v22: 16 waves (1024 thr), 4 waves/SIMD -----
// Same verified v19 math/swizzles/pipeline (QBLK=128, split=2, ONE barrier per
// tile, P dbuf, fp8 Q/K + bf16 V/P). New: ONE 1024-thread block per CU = 16
// waves = 4 waves/SIMD (sidesteps the measured no-co-residency wall, which
// applies only to separate workgroups). Waves = (qq: 32q quarter) x (sub:
// 16kv-slice in QK / 64d-slice in PV). Total LDS traffic ~flat (only P-reads
// x2); per-wave registers DROP (o[2][4]) so the 4-wave 128-VGPR cap fits.
// LDS 128KB: K fp8 dbuf 2x16K @0 | V bf16 dbuf 2x32K @32K | P dbuf 2x16K @96K.
#define VVB 32768u
#define PVB 98304u

#define PV_STEP(SLOT)                                                          \
  {                                                                            \
    bf16x8 pfr[2][2];                                                          \
    _Pragma("unroll") for (int mt = 0; mt < 2; ++mt)                           \
    _Pragma("unroll") for (int j2 = 0; j2 < 2; ++j2)                           \
        pfr[mt][j2] = *(const bf16x8*)(lds + PVB + (SLOT) * 16384 + pro[j2] +  \
                                       mt * 2048);                             \
    __builtin_amdgcn_s_setprio(1);                                             \
    _Pragma("unroll") for (int mt = 0; mt < 2; ++mt)                           \
    _Pragma("unroll") for (int j2 = 0; j2 < 2; ++j2)                           \
        lacc[mt] = __builtin_amdgcn_mfma_f32_16x16x32_bf16(pfr[mt][j2], ones,  \
                                                           lacc[mt], 0, 0, 0); \
    _Pragma("unroll") for (int d0 = 0; d0 < 4; ++d0)                           \
    _Pragma("unroll") for (int j2 = 0; j2 < 2; ++j2) {                         \
      bf16x8 vfr = *(const bf16x8*)(lds + VVB + (SLOT) * 32768 + vro[j2] +     \
                                    d0 * 2048);                                \
      o[0][d0] = __builtin_amdgcn_mfma_f32_16x16x32_bf16(pfr[0][j2], vfr, o[0][d0], 0, 0, 0); \
      o[1][d0] = __builtin_amdgcn_mfma_f32_16x16x32_bf16(pfr[1][j2], vfr, o[1][d0], 0, 0, 0); \
    }                                                                          \
    __builtin_amdgcn_s_setprio(0);                                             \
  }

#define TILE(CUR, DO_PV, DO_K)                                                 \
  {                                                                            \
    asm volatile("s_waitcnt vmcnt(0) lgkmcnt(0)" ::: "memory");                \
    __builtin_amdgcn_s_barrier();                                              \
    __builtin_amdgcn_sched_barrier(0);                                         \
    gload_lds16(vstp + vso[0], lds + VVB + (CUR) * 32768 + (w * 2 + 0) * 1024); \
    gload_lds16(vstp + vso[1], lds + VVB + (CUR) * 32768 + (w * 2 + 1) * 1024); \
    if (DO_K)                                                                  \
      gload_lds16(kstp + kso0, lds + ((CUR) ^ 1) * 16384 + w * 1024);          \
    kstp += 16384;                                                             \
    vstp += 32768;                                                             \
    f32x4 sc[2];                                                               \
    sc[0] = (f32x4){0.f, 0.f, 0.f, 0.f};                                       \
    sc[1] = (f32x4){0.f, 0.f, 0.f, 0.f};                                       \
    __builtin_amdgcn_s_setprio(1);                                             \
    _Pragma("unroll") for (int j = 0; j < 8; ++j) {                            \
      i64 kfr = *(const i64*)(lds + (CUR) * 16384 + kro[j]);                   \
      sc[0] = mfma8(kfr, qfr[0][j], sc[0]);                                    \
      sc[1] = mfma8(kfr, qfr[1][j], sc[1]);                                    \
    }                                                                          \
    __builtin_amdgcn_s_setprio(0);                                             \
    _Pragma("unroll") for (int mt = 0; mt < 2; ++mt) {                         \
      float e0 = exp2f(sc[mt][0]);                                             \
      float e1 = exp2f(sc[mt][1]);                                             \
      float e2 = exp2f(sc[mt][2]);                                             \
      float e3 = exp2f(sc[mt][3]);                                             \
      uint32_t p0 = (uint32_t)f2bf(e0) | ((uint32_t)f2bf(e1) << 16);           \
      uint32_t p1 = (uint32_t)f2bf(e2) | ((uint32_t)f2bf(e3) << 16);           \
      u32x2 pk = {p0, p1};                                                     \
      *(u32x2*)(lds + PVB + (CUR) * 16384 + pwo + mt * 2048) = pk;             \
    }                                                                          \
    if (DO_PV) PV_STEP((CUR) ^ 1)                                              \
  }

__global__ __launch_bounds__(1024, 1) void attn_kernel(
    const uint8_t* __restrict__ qs, const uint8_t* __restrict__ kk,
    const char* __restrict__ vt, float* __restrict__ out,
    u16* __restrict__ pOB, float* __restrict__ pl, int split) {
  __shared__ __align__(16) char lds[131072];
  int tid = threadIdx.x;
  int w = tid >> 6, l = tid & 63;           // w: 0..15
  int a = l & 15, g = l >> 4;
  int qq = w >> 2, sub = w & 3;             // qq: 32q quarter; sub: kv/d slice
  int bx = blockIdx.x;
  int h, batch, qt;
  // XCD-pinning: (batch,h) <-> XCD pair; fp8 K + bf16 V halves stay L2-resident
  if (split == 2) { h = bx & 1; batch = (bx >> 1) & 3; qt = bx >> 3; }
  else            { h = 0;      batch = (bx >> 1) & 3; qt = ((bx >> 3) << 1) | (bx & 1); }
  int ntHalf = (split == 2) ? 16 : 32;

  uint32_t a7 = a & 7;
  // ---- hoisted LDS byte offsets (v19-verified forms, finer wave slicing) ---
  uint32_t kro[8], vro[2], pro[2], pwo, kso0, vso[2];
  {
    uint32_t row = (uint32_t)(sub * 16 + a);   // K fp8: 64 rows x 256B
#pragma unroll
    for (int j = 0; j < 8; ++j) {
      uint32_t c4 = j * 2 + (g >> 1);
      kro[j] = row * 256 + (((c4 & ~7u) | ((c4 ^ a7) & 7u)) << 4) + (g & 1) * 8;
    }
  }
#pragma unroll
  for (int j2 = 0; j2 < 2; ++j2)               // V bf16: 256 rows x 128B
    vro[j2] = (uint32_t)(sub * 64 + a) * 128 +
              ((((uint32_t)(j2 * 4 + g)) ^ a7) << 4);
  {
    uint32_t q = (uint32_t)(qq * 32 + a);      // P bf16: 128 rows x 128B
#pragma unroll
    for (int j2 = 0; j2 < 2; ++j2)
      pro[j2] = q * 128 + ((((uint32_t)(j2 * 4 + g)) ^ a7) << 4);
    uint32_t tg = (uint32_t)(sub * 2 + (g >> 1));
    pwo = q * 128 + ((tg ^ a7) << 4) + (g & 1) * 8;
  }
  {                                            // K stage: 16 instrs, 1/wave
    uint32_t flat = (uint32_t)w * 1024 + l * 16;
    uint32_t row = flat >> 8, c4 = (flat >> 4) & 15;
    kso0 = row * 256 + (((c4 & ~7u) | ((c4 ^ (row & 7u)) & 7u)) << 4);
  }
#pragma unroll
  for (int j = 0; j < 2; ++j) {                // V stage: 32 instrs, 2/wave
    uint32_t inst = w * 2 + j, flat = inst * 1024 + l * 16;
    uint32_t row = flat >> 7, c3 = (flat >> 4) & 7;
    vso[j] = row * 128 + ((c3 ^ (row & 7)) << 4);
  }

  // Q fragments fp8 (B-operand): 32 q-rows of quarter qq
  i64 qfr[2][8];
  {
    const uint8_t* qp = qs + (size_t)(batch * SEQ + qt * 128) * 256;
#pragma unroll
    for (int mt = 0; mt < 2; ++mt)
#pragma unroll
      for (int j = 0; j < 8; ++j)
        qfr[mt][j] = *(const i64*)(qp + (size_t)(qq * 32 + mt * 16 + a) * 256 +
                                   j * 32 + g * 8);
  }

  f32x4 o[2][4];   // O[32q][64d] (d-slice sub), unnormalized partial
  f32x4 lacc[2];   // partial row-sums of P (identical across sub; store sub==0)
#pragma unroll
  for (int mt = 0; mt < 2; ++mt) {
    lacc[mt] = (f32x4){0.f, 0.f, 0.f, 0.f};
#pragma unroll
    for (int d0 = 0; d0 < 4; ++d0) o[mt][d0] = (f32x4){0.f, 0.f, 0.f, 0.f};
  }
  const short ob = (short)0x3F80;
  bf16x8 ones = {ob, ob, ob, ob, ob, ob, ob, ob};

  const uint8_t* kstp = kk + (size_t)batch * SEQ * 256 + (size_t)h * 2048 * 256;
  const char* vstp = vt + (size_t)batch * 64 * 32768 + (size_t)h * 32 * 32768;

  // prologue: stage K(0) into slot 0
  gload_lds16(kstp + kso0, lds + w * 1024);
  kstp += 16384;

  TILE(0, false, true)                       // t = 0
  for (int tp = 0; tp < ntHalf - 1; ++tp) {  // t = 1..nt-2
    TILE(1, true, true)
    TILE(0, true, true)
  }
  TILE(1, true, false)                       // t = nt-1 (no K stage)

  // ---- epilogue: PV(nt-1) from slot 1, then store partials ----------------
  asm volatile("s_waitcnt vmcnt(0) lgkmcnt(0)" ::: "memory");
  __builtin_amdgcn_s_barrier();
  __builtin_amdgcn_sched_barrier(0);
  PV_STEP(1)

  size_t obase = (size_t)(batch * SEQ + qt * 128 + qq * 32) * 256 + sub * 64;
  if (h == 0) {
#pragma unroll
    for (int mt = 0; mt < 2; ++mt)
#pragma unroll
      for (int r = 0; r < 4; ++r) {
#pragma unroll
        for (int d0 = 0; d0 < 4; ++d0)
          out[obase + (size_t)(mt * 16 + g * 4 + r) * 256 + d0 * 16 + a] = o[mt][d0][r];
      }
  } else {
#pragma unroll
    for (int mt = 0; mt < 2; ++mt)
#pragma unroll
      for (int r = 0; r < 4; ++r) {
#pragma unroll
        for (int d0 = 0; d0 < 4; ++d0)
          pOB[obase + (size_t)(mt * 16 + g * 4 + r) * 256 + d0 * 16 + a] =
              f2bf(o[mt][d0][r]);
      }
  }
  if (a == 0 && sub == 0) {
#pragma unroll
    for (int mt = 0; mt < 2; ++mt)
#pragma unroll
      for (int r = 0; r < 4; ++r)
        pl[h * 16384 + (batch * 32 + qt) * 128 + qq * 32 + mt * 16 + g * 4 + r] =
            lacc[mt][r];
  }
}

// ---------------- combine: out = (OA + OB) / (lA + lB), OB bf16 --------------
__global__ __launch_bounds__(256) void combine_kernel(float* __restrict__ out,
                                                      const u16* __restrict__ pOB,
                                                      const float* __restrict__ pl,
                                                      int split) {
  int b = blockIdx.x;            // 16384 rows
  int tid = threadIdx.x;
  int batch = b >> 12;
  int rem = b & 4095;
  int qt = rem >> 7, ql = rem & 127;
  size_t idx = (size_t)b * 256 + tid;
  int li = (batch * 32 + qt) * 128 + ql;
  float lA = pl[li];
  float v;
  if (split == 2) {
    float lB = pl[16384 + li];
    v = (out[idx] + bf2f(pOB[idx])) / (lA + lB);
  } else {
    v = out[idx] / lA;
  }
  out[idx] = v;
}

extern "C" void kernel_launch(void* const* d_in, const int* in_sizes, int n_in,
                              void* d_out, int out_size, void* d_ws, size_t ws_size,
                              hipStream_t stream) {
  const float* x = (const float*)d_in[0];
  const float* Wq = (const float*)d_in[1];
  const float* bq = (const float*)d_in[2];
  const float* Wk = (const float*)d_in[3];
  const float* bk = (const float*)d_in[4];
  const float* Wv = (const float*)d_in[5];
  const float* bv = (const float*)d_in[6];
  char* ws = (char*)d_ws;
  u16* wt = (u16*)ws;                              // 384KB @0
  uint8_t* qs = (uint8_t*)(ws + 0x60000);          // 4MB fp8 Q
  uint8_t* kk = (uint8_t*)(ws + 0x460000);         // 4MB fp8 K
  char* vt = ws + 0x860000;                        // 8MB bf16 V^T
  float* pl = (float*)(ws + 0x1060000);            // 128KB
  u16* pOB = (u16*)(ws + 0x1080000);               // 8MB bf16 partial O (h=1)
  int split = (ws_size >= 0x1880000ull) ? 2 : 1;
  wt_kernel<<<dim3(768), dim3(256), 0, stream>>>(Wq, Wk, Wv, wt);
  qkv_kernel<<<dim3(256), dim3(256), 0, stream>>>(x, bq, bk, bv, wt, qs, kk, vt);
  attn_kernel<<<dim3(split * 128), dim3(1024), 0, stream>>>(qs, kk, vt, (float*)d_out,
                                                            pOB, pl, split);
  combine_kernel<<<dim3(16384), dim3(256), 0, stream>>>((float*)d_out, pOB, pl, split);
}

// Round 23
// 109.962 us; speedup vs baseline: 1.0983x; 1.0376x over previous
//
#include <hip/hip_runtime.h>
#include <stdint.h>

typedef unsigned short u16;
typedef long long i64;
typedef __attribute__((ext_vector_type(4))) float f32x4;
typedef __attribute__((ext_vector_type(8))) short bf16x8;
typedef __attribute__((ext_vector_type(4))) int i32x4;
typedef __attribute__((ext_vector_type(2))) unsigned int u32x2;

#define SEQ 4096
#define DIM 256
// base scale = 1/sqrt(256)*log2(e); Q folds x4, K folds 0.25 (fp8 range balance)
#define QS4 0.36067376f

__device__ __forceinline__ u16 f2bf(float f) {
  union { float f; uint32_t u; } v; v.f = f;
  uint32_t r = (v.u + 0x7FFFu + ((v.u >> 16) & 1u)) >> 16;
  return (u16)r;
}

__device__ __forceinline__ float bf2f(u16 u) {
  union { uint32_t u; float f; } v; v.u = ((uint32_t)u) << 16;
  return v.f;
}

__device__ __forceinline__ uint8_t f2fp8(float f) {
  return (uint8_t)__builtin_amdgcn_cvt_pk_fp8_f32(f, 0.f, 0, false);
}

__device__ __forceinline__ void gload_lds16(const void* g, void* lds) {
  __builtin_amdgcn_global_load_lds(
      (const __attribute__((address_space(1))) uint32_t*)g,
      (__attribute__((address_space(3))) uint32_t*)lds, 16, 0, 0);
}

__device__ __forceinline__ f32x4 mfma8(i64 a, i64 b, f32x4 c) {
  return __builtin_amdgcn_mfma_f32_16x16x32_fp8_fp8(a, b, c, 0, 0, 0);
}

// ---------------- weight transpose + bf16 cast (scales folded) ---------------
__global__ __launch_bounds__(256) void wt_kernel(const float* __restrict__ Wq,
                                                 const float* __restrict__ Wk,
                                                 const float* __restrict__ Wv,
                                                 u16* __restrict__ wt) {
  int b = blockIdx.x;              // 0..767
  int w = b >> 8;                  // which matrix
  int n = b & 255;                 // output column -> wt row
  const float* W = (w == 0) ? Wq : ((w == 1) ? Wk : Wv);
  float scale = (w == 0) ? QS4 : ((w == 1) ? 0.25f : 1.0f);
  int k = threadIdx.x;
  wt[(w * 256 + n) * 256 + k] = f2bf(W[k * 256 + n] * scale);
}

// ---------------- QKV v3: dbuf staging, f32x4 x-loads, bias in LDS -----------
__global__ __launch_bounds__(256) void qkv_kernel(
    const float* __restrict__ x, const float* __restrict__ bq,
    const float* __restrict__ bk, const float* __restrict__ bv,
    const u16* __restrict__ wt, uint8_t* __restrict__ qs,
    uint8_t* __restrict__ kk, char* __restrict__ vt) {
  __shared__ __align__(16) char lds_b[65536];   // 2 x 32KB weight chunks
  __shared__ __align__(16) u16 lds_v[4096];     // 8KB V-transpose buffer
  __shared__ float lds_bias[768];               // pre-scaled biases
  int tid = threadIdx.x;
  int w = tid >> 6, l = tid & 63;
  int a = l & 15, g = l >> 4;
  int rowbase = blockIdx.x * 64;

  // bias preload (scales folded); visible after the loop-top barrier
  lds_bias[tid] = bq[tid] * QS4;
  lds_bias[256 + tid] = bk[tid] * 0.25f;
  lds_bias[512 + tid] = bv[tid];

  uint32_t wso[8];
#pragma unroll
  for (int j = 0; j < 8; ++j) {
    uint32_t inst = w * 8 + j;
    uint32_t flat = inst * 1024 + l * 16;
    uint32_t row = flat >> 9;
    uint32_t c5 = (flat >> 4) & 31;
    uint32_t sc = (c5 & ~7u) | ((c5 ^ row) & 7u);
    wso[j] = row * 512 + sc * 16;
  }
  uint32_t bro[8];
#pragma unroll
  for (int ks = 0; ks < 8; ++ks) {
    uint32_t c5 = ks * 4 + g;
    uint32_t sc = (c5 & ~7u) | ((c5 ^ (a & 7u)) & 7u);
    bro[ks] = (uint32_t)a * 512 + sc * 16;
  }

  // prologue staging first so transfers start earliest
#pragma unroll
  for (int j = 0; j < 8; ++j)
    gload_lds16((const char*)wt + wso[j], lds_b + (w * 8 + j) * 1024);

  bf16x8 afr[8];
  {
    int row = rowbase + w * 16 + a;
    const f32x4* xr4 = (const f32x4*)(x + (size_t)row * 256);
#pragma unroll
    for (int ks = 0; ks < 8; ++ks) {
      int q4 = ks * 8 + g * 2;
      f32x4 lo = xr4[q4], hi = xr4[q4 + 1];
      union { bf16x8 s; u16 u[8]; } fr;
      fr.u[0] = f2bf(lo[0]); fr.u[1] = f2bf(lo[1]);
      fr.u[2] = f2bf(lo[2]); fr.u[3] = f2bf(lo[3]);
      fr.u[4] = f2bf(hi[0]); fr.u[5] = f2bf(hi[1]);
      fr.u[6] = f2bf(hi[2]); fr.u[7] = f2bf(hi[3]);
      afr[ks] = fr.s;
    }
  }

  int cur = 0;
  for (int it = 0; it < 12; ++it) {
    asm volatile("s_waitcnt vmcnt(0) lgkmcnt(0)" ::: "memory");
    __builtin_amdgcn_s_barrier();
    __builtin_amdgcn_sched_barrier(0);
    if (it < 11) {
#pragma unroll
      for (int j = 0; j < 8; ++j)
        gload_lds16((const char*)wt + (size_t)(it + 1) * 32768 + wso[j],
                    lds_b + (cur ^ 1) * 32768 + (w * 8 + j) * 1024);
    }
    int w3 = it >> 2, qn = it & 3;
    f32x4 acc[4];
#pragma unroll
    for (int n0 = 0; n0 < 4; ++n0) acc[n0] = (f32x4){0.f, 0.f, 0.f, 0.f};
#pragma unroll
    for (int ks = 0; ks < 8; ++ks) {
#pragma unroll
      for (int n0 = 0; n0 < 4; ++n0) {
        bf16x8 bfr = *(const bf16x8*)(lds_b + cur * 32768 + bro[ks] + n0 * 8192);
        acc[n0] = __builtin_amdgcn_mfma_f32_16x16x32_bf16(afr[ks], bfr, acc[n0], 0, 0, 0);
      }
    }
    if (w3 < 2) {
      uint8_t* out8 = (w3 == 0) ? qs : kk;
#pragma unroll
      for (int n0 = 0; n0 < 4; ++n0) {
        int col = qn * 64 + n0 * 16 + a;
        float bb = lds_bias[w3 * 256 + col];
#pragma unroll
        for (int r = 0; r < 4; ++r) {
          int row = rowbase + w * 16 + g * 4 + r;
          out8[(size_t)row * 256 + col] = f2fp8(acc[n0][r] + bb);
        }
      }
    } else {
#pragma unroll
      for (int n0 = 0; n0 < 4; ++n0) {
        int col = qn * 64 + n0 * 16 + a;
        float bb = lds_bias[512 + col];
        int dl = n0 * 16 + a;
#pragma unroll
        for (int r = 0; r < 4; ++r) {
          int m = w * 16 + g * 4 + r;
          uint32_t byteoff =
              (uint32_t)dl * 128 + ((((uint32_t)m >> 3) ^ ((uint32_t)dl & 7)) << 4) + (m & 7) * 2;
          *(u16*)((char*)lds_v + byteoff) = f2bf(acc[n0][r] + bb);
        }
      }
      asm volatile("s_waitcnt lgkmcnt(0)" ::: "memory");
      __builtin_amdgcn_s_barrier();   // lds_v writes visible; no vmcnt drain
      {
        int dl = tid >> 2;
        size_t base = (size_t)blockIdx.x * 32768 + (size_t)(qn * 64 + dl) * 128;
#pragma unroll
        for (int cc = 0; cc < 2; ++cc) {
          uint32_t c = (tid & 3) + cc * 4;
          i32x4 vd = *(const i32x4*)((const char*)lds_v + dl * 128 + ((c ^ (dl & 7)) << 4));
          *(i32x4*)(vt + base + c * 16) = vd;
        }
      }
    }
    cur ^= 1;
  }
}

// ---------------- flash attention v23: v22 + lacc computed by sub==0 only ----
// v22 verified: 1024-thread block (16 waves, 4/SIMD), QBLK=128, split=2, ONE
// barrier/tile, P dbuf, fp8 Q/K + bf16 V/P, absmax 1.95e-3. New: the 4 sub
// slices compute identical row-sums; only sub==0 stores them -> wave-uniform
// skip of the 4 lacc MFMAs for sub!=0 (12 of 16 waves).
// LDS 128KB: K fp8 dbuf 2x16K @0 | V bf16 dbuf 2x32K @32K | P dbuf 2x16K @96K.
#define VVB 32768u
#define PVB 98304u

#define PV_STEP(SLOT)                                                          \
  {                                                                            \
    bf16x8 pfr[2][2];                                                          \
    _Pragma("unroll") for (int mt = 0; mt < 2; ++mt)                           \
    _Pragma("unroll") for (int j2 = 0; j2 < 2; ++j2)                           \
        pfr[mt][j2] = *(const bf16x8*)(lds + PVB + (SLOT) * 16384 + pro[j2] +  \
                                       mt * 2048);                             \
    __builtin_amdgcn_s_setprio(1);                                             \
    if (sub == 0) {                                                            \
      _Pragma("unroll") for (int mt = 0; mt < 2; ++mt)                         \
      _Pragma("unroll") for (int j2 = 0; j2 < 2; ++j2)                         \
          lacc[mt] = __builtin_amdgcn_mfma_f32_16x16x32_bf16(pfr[mt][j2], ones,\
                                                             lacc[mt], 0, 0, 0); \
    }                                                                          \
    _Pragma("unroll") for (int d0 = 0; d0 < 4; ++d0)                           \
    _Pragma("unroll") for (int j2 = 0; j2 < 2; ++j2) {                         \
      bf16x8 vfr = *(const bf16x8*)(lds + VVB + (SLOT) * 32768 + vro[j2] +     \
                                    d0 * 2048);                                \
      o[0][d0] = __builtin_amdgcn_mfma_f32_16x16x32_bf16(pfr[0][j2], vfr, o[0][d0], 0, 0, 0); \
      o[1][d0] = __builtin_amdgcn_mfma_f32_16x16x32_bf16(pfr[1][j2], vfr, o[1][d0], 0, 0, 0); \
    }                                                                          \
    __builtin_amdgcn_s_setprio(0);                                             \
  }

#define TILE(CUR, DO_PV, DO_K)                                                 \
  {                                                                            \
    asm volatile("s_waitcnt vmcnt(0) lgkmcnt(0)" ::: "memory");                \
    __builtin_amdgcn_s_barrier();                                              \
    __builtin_amdgcn_sched_barrier(0);                                         \
    gload_lds16(vstp + vso[0], lds + VVB + (CUR) * 32768 + (w * 2 + 0) * 1024); \
    gload_lds16(vstp + vso[1], lds + VVB + (CUR) * 32768 + (w * 2 + 1) * 1024); \
    if (DO_K)                                                                  \
      gload_lds16(kstp + kso0, lds + ((CUR) ^ 1) * 16384 + w * 1024);          \
    kstp += 16384;                                                             \
    vstp += 32768;                                                             \
    f32x4 sc[2];                                                               \
    sc[0] = (f32x4){0.f, 0.f, 0.f, 0.f};                                       \
    sc[1] = (f32x4){0.f, 0.f, 0.f, 0.f};                                       \
    __builtin_amdgcn_s_setprio(1);                                             \
    _Pragma("unroll") for (int j = 0; j < 8; ++j) {                            \
      i64 kfr = *(const i64*)(lds + (CUR) * 16384 + kro[j]);                   \
      sc[0] = mfma8(kfr, qfr[0][j], sc[0]);                                    \
      sc[1] = mfma8(kfr, qfr[1][j], sc[1]);                                    \
    }                                                                          \
    __builtin_amdgcn_s_setprio(0);                                             \
    _Pragma("unroll") for (int mt = 0; mt < 2; ++mt) {                         \
      float e0 = exp2f(sc[mt][0]);                                             \
      float e1 = exp2f(sc[mt][1]);                                             \
      float e2 = exp2f(sc[mt][2]);                                             \
      float e3 = exp2f(sc[mt][3]);                                             \
      uint32_t p0 = (uint32_t)f2bf(e0) | ((uint32_t)f2bf(e1) << 16);           \
      uint32_t p1 = (uint32_t)f2bf(e2) | ((uint32_t)f2bf(e3) << 16);           \
      u32x2 pk = {p0, p1};                                                     \
      *(u32x2*)(lds + PVB + (CUR) * 16384 + pwo + mt * 2048) = pk;             \
    }                                                                          \
    if (DO_PV) PV_STEP((CUR) ^ 1)                                              \
  }

__global__ __launch_bounds__(1024, 1) void attn_kernel(
    const uint8_t* __restrict__ qs, const uint8_t* __restrict__ kk,
    const char* __restrict__ vt, float* __restrict__ out,
    u16* __restrict__ pOB, float* __restrict__ pl, int split) {
  __shared__ __align__(16) char lds[131072];
  int tid = threadIdx.x;
  int w = tid >> 6, l = tid & 63;           // w: 0..15
  int a = l & 15, g = l >> 4;
  int qq = w >> 2, sub = w & 3;             // qq: 32q quarter; sub: kv/d slice
  int bx = blockIdx.x;
  int h, batch, qt;
  // XCD-pinning: (batch,h) <-> XCD pair; fp8 K + bf16 V halves stay L2-resident
  if (split == 2) { h = bx & 1; batch = (bx >> 1) & 3; qt = bx >> 3; }
  else            { h = 0;      batch = (bx >> 1) & 3; qt = ((bx >> 3) << 1) | (bx & 1); }
  int ntHalf = (split == 2) ? 16 : 32;

  uint32_t a7 = a & 7;
  // ---- hoisted LDS byte offsets (v22-verified forms) -----------------------
  uint32_t kro[8], vro[2], pro[2], pwo, kso0, vso[2];
  {
    uint32_t row = (uint32_t)(sub * 16 + a);   // K fp8: 64 rows x 256B
#pragma unroll
    for (int j = 0; j < 8; ++j) {
      uint32_t c4 = j * 2 + (g >> 1);
      kro[j] = row * 256 + (((c4 & ~7u) | ((c4 ^ a7) & 7u)) << 4) + (g & 1) * 8;
    }
  }
#pragma unroll
  for (int j2 = 0; j2 < 2; ++j2)               // V bf16: 256 rows x 128B
    vro[j2] = (uint32_t)(sub * 64 + a) * 128 +
              ((((uint32_t)(j2 * 4 + g)) ^ a7) << 4);
  {
    uint32_t q = (uint32_t)(qq * 32 + a);      // P bf16: 128 rows x 128B
#pragma unroll
    for (int j2 = 0; j2 < 2; ++j2)
      pro[j2] = q * 128 + ((((uint32_t)(j2 * 4 + g)) ^ a7) << 4);
    uint32_t tg = (uint32_t)(sub * 2 + (g >> 1));
    pwo = q * 128 + ((tg ^ a7) << 4) + (g & 1) * 8;
  }
  {                                            // K stage: 16 instrs, 1/wave
    uint32_t flat = (uint32_t)w * 1024 + l * 16;
    uint32_t row = flat >> 8, c4 = (flat >> 4) & 15;
    kso0 = row * 256 + (((c4 & ~7u) | ((c4 ^ (row & 7u)) & 7u)) << 4);
  }
#pragma unroll
  for (int j = 0; j < 2; ++j) {                // V stage: 32 instrs, 2/wave
    uint32_t inst = w * 2 + j, flat = inst * 1024 + l * 16;
    uint32_t row = flat >> 7, c3 = (flat >> 4) & 7;
    vso[j] = row * 128 + ((c3 ^ (row & 7)) << 4);
  }

  // Q fragments fp8 (B-operand): 32 q-rows of quarter qq
  i64 qfr[2][8];
  {
    const uint8_t* qp = qs + (size_t)(batch * SEQ + qt * 128) * 256;
#pragma unroll
    for (int mt = 0; mt < 2; ++mt)
#pragma unroll
      for (int j = 0; j < 8; ++j)
        qfr[mt][j] = *(const i64*)(qp + (size_t)(qq * 32 + mt * 16 + a) * 256 +
                                   j * 32 + g * 8);
  }

  f32x4 o[2][4];   // O[32q][64d] (d-slice sub), unnormalized partial
  f32x4 lacc[2];   // partial row-sums of P (computed+stored by sub==0 only)
#pragma unroll
  for (int mt = 0; mt < 2; ++mt) {
    lacc[mt] = (f32x4){0.f, 0.f, 0.f, 0.f};
#pragma unroll
    for (int d0 = 0; d0 < 4; ++d0) o[mt][d0] = (f32x4){0.f, 0.f, 0.f, 0.f};
  }
  const short ob = (short)0x3F80;
  bf16x8 ones = {ob, ob, ob, ob, ob, ob, ob, ob};

  const uint8_t* kstp = kk + (size_t)batch * SEQ * 256 + (size_t)h * 2048 * 256;
  const char* vstp = vt + (size_t)batch * 64 * 32768 + (size_t)h * 32 * 32768;

  // prologue: stage K(0) into slot 0
  gload_lds16(kstp + kso0, lds + w * 1024);
  kstp += 16384;

  TILE(0, false, true)                       // t = 0
  for (int tp = 0; tp < ntHalf - 1; ++tp) {  // t = 1..nt-2
    TILE(1, true, true)
    TILE(0, true, true)
  }
  TILE(1, true, false)                       // t = nt-1 (no K stage)

  // ---- epilogue: PV(nt-1) from slot 1, then store partials ----------------
  asm volatile("s_waitcnt vmcnt(0) lgkmcnt(0)" ::: "memory");
  __builtin_amdgcn_s_barrier();
  __builtin_amdgcn_sched_barrier(0);
  PV_STEP(1)

  size_t obase = (size_t)(batch * SEQ + qt * 128 + qq * 32) * 256 + sub * 64;
  if (h == 0) {
#pragma unroll
    for (int mt = 0; mt < 2; ++mt)
#pragma unroll
      for (int r = 0; r < 4; ++r) {
#pragma unroll
        for (int d0 = 0; d0 < 4; ++d0)
          out[obase + (size_t)(mt * 16 + g * 4 + r) * 256 + d0 * 16 + a] = o[mt][d0][r];
      }
  } else {
#pragma unroll
    for (int mt = 0; mt < 2; ++mt)
#pragma unroll
      for (int r = 0; r < 4; ++r) {
#pragma unroll
        for (int d0 = 0; d0 < 4; ++d0)
          pOB[obase + (size_t)(mt * 16 + g * 4 + r) * 256 + d0 * 16 + a] =
              f2bf(o[mt][d0][r]);
      }
  }
  if (a == 0 && sub == 0) {
#pragma unroll
    for (int mt = 0; mt < 2; ++mt)
#pragma unroll
      for (int r = 0; r < 4; ++r)
        pl[h * 16384 + (batch * 32 + qt) * 128 + qq * 32 + mt * 16 + g * 4 + r] =
            lacc[mt][r];
  }
}

// ---------------- combine: out = (OA + OB) / (lA + lB), OB bf16 --------------
__global__ __launch_bounds__(256) void combine_kernel(float* __restrict__ out,
                                                      const u16* __restrict__ pOB,
                                                      const float* __restrict__ pl,
                                                      int split) {
  int b = blockIdx.x;            // 16384 rows
  int tid = threadIdx.x;
  int batch = b >> 12;
  int rem = b & 4095;
  int qt = rem >> 7, ql = rem & 127;
  size_t idx = (size_t)b * 256 + tid;
  int li = (batch * 32 + qt) * 128 + ql;
  float lA = pl[li];
  float v;
  if (split == 2) {
    float lB = pl[16384 + li];
    v = (out[idx] + bf2f(pOB[idx])) / (lA + lB);
  } else {
    v = out[idx] / lA;
  }
  out[idx] = v;
}

extern "C" void kernel_launch(void* const* d_in, const int* in_sizes, int n_in,
                              void* d_out, int out_size, void* d_ws, size_t ws_size,
                              hipStream_t stream) {
  const float* x = (const float*)d_in[0];
  const float* Wq = (const float*)d_in[1];
  const float* bq = (const float*)d_in[2];
  const float* Wk = (const float*)d_in[3];
  const float* bk = (const float*)d_in[4];
  const float* Wv = (const float*)d_in[5];
  const float* bv = (const float*)d_in[6];
  char* ws = (char*)d_ws;
  u16* wt = (u16*)ws;                              // 384KB @0
  uint8_t* qs = (uint8_t*)(ws + 0x60000);          // 4MB fp8 Q
  uint8_t* kk = (uint8_t*)(ws + 0x460000);         // 4MB fp8 K
  char* vt = ws + 0x860000;                        // 8MB bf16 V^T
  float* pl = (float*)(ws + 0x1060000);            // 128KB
  u16* pOB = (u16*)(ws + 0x1080000);               // 8MB bf16 partial O (h=1)
  int split = (ws_size >= 0x1880000ull) ? 2 : 1;
  wt_kernel<<<dim3(768), dim3(256), 0, stream>>>(Wq, Wk, Wv, wt);
  qkv_kernel<<<dim3(256), dim3(256), 0, stream>>>(x, bq, bk, bv, wt, qs, kk, vt);
  attn_kernel<<<dim3(split * 128), dim3(1024), 0, stream>>>(qs, kk, vt, (float*)d_out,
                                                            pOB, pl, split);
  combine_kernel<<<dim3(16384), dim3(256), 0, stream>>>((float*)d_out, pOB, pl, split);
}